// Round 8
// baseline (232.091 us; speedup 1.0000x reference)
//
#include <hip/hip_runtime.h>

// IWT (inverse 2x2 Haar): x (32, 256, 64, 64) f32 -> out (32, 64, 128, 128) f32
// Input channel dim = 64 groups * 4 subbands {cA, cH, cV, cD}.
// out[2h  ][2w  ] = (a + h + v + d) * 0.5
// out[2h  ][2w+1] = (a + h - v - d) * 0.5
// out[2h+1][2w  ] = (a - h + v - d) * 0.5
// out[2h+1][2w+1] = (a - h - v + d) * 0.5
//
// v6: copy-shaped kernel via LDS staging. (Resubmitted after infra failure.)
//   Evidence: v1..v5 exhausted per-wave levers (width/MLP/NT/persistence/
//   block size) — all null or negative; kernel stuck at ~4.4 TB/s demand
//   while fills (1 stream) hit 6.6 and copy (2 streams) 6.29 on the same
//   chip with nothing saturated. Common property of all five: each wave
//   reads 4 streams at exact 16 KiB offsets + writes 2 interleaved
//   segments. Input layout is kind: the 4 subbands of one bc are ONE
//   contiguous 64 KiB region, and its output is ONE contiguous 64 KiB
//   region. So: one block per bc; stage 64 KiB input to LDS with
//   global_load_lds width=16 (linear LDS = linear global — the verified
//   m97 pattern), barrier, butterfly from LDS (all ds_read_b64 512B
//   wave-contiguous, conflict-free), store dense to the contiguous output
//   window. DRAM now sees a 64 KiB-granular memcpy.

#define NTHREAD 256
#define NBLOCK  2048   // one block per bc

typedef float f32x2 __attribute__((ext_vector_type(2)));
typedef float f32x4 __attribute__((ext_vector_type(4)));

__global__ __launch_bounds__(NTHREAD) void iwt_kernel(const float* __restrict__ x,
                                                      f32x4* __restrict__ ov) {
    __shared__ float lds[16384];   // 64 KiB: the block's (4,64,64) input slab

    const int bc   = blockIdx.x;
    const int wave = threadIdx.x >> 6;
    const int lane = threadIdx.x & 63;

    // ---- Phase 1: stage 64 KiB contiguous input -> LDS (linear) ----
    // 16 chunks of 1 KiB per wave-instruction; 4 waves x 16 iters = 64 KiB.
    const char* gbase = (const char*)x + ((size_t)bc << 16);
    char* lbase = (char*)lds;
    #pragma unroll
    for (int t = 0; t < 16; ++t) {
        int off = (((t << 2) + wave) << 10) + (lane << 4);   // bytes
        __builtin_amdgcn_global_load_lds(
            (const __attribute__((address_space(1))) unsigned int*)(gbase + off),
            (__attribute__((address_space(3))) unsigned int*)(lbase + off),
            16, 0, 0);
    }
    __syncthreads();   // drains vmcnt before s_barrier (compiler-enforced)

    // ---- Phase 2: butterfly from LDS, dense stores to contiguous window ----
    // tile t = threadIdx.x + 256*k, k=0..7:  w2 = tix&31, h = (tix>>5) + 8k
    // LDS f32x2 idx for subband s: s*2048 + h*32 + w2
    //   lanes 0..31 read 256B contiguous, lanes 32..63 the next 256B -> free.
    // out f32x4 idx (within bc window): row 2h at h*64 + w2, row 2h+1 at +32.
    const f32x2* l2 = (const f32x2*)lds;
    f32x4* ob = ov + (bc << 12);
    const int w2 = threadIdx.x & 31;
    const int hb = threadIdx.x >> 5;   // 0..7

    #pragma unroll
    for (int k = 0; k < 8; ++k) {
        int h  = hb + (k << 3);
        int li = (h << 5) + w2;
        f32x2 a  = l2[li];
        f32x2 hh = l2[li + 2048];
        f32x2 v  = l2[li + 4096];
        f32x2 d  = l2[li + 6144];

        float px = a.x + d.x, qx = a.x - d.x, rx = hh.x + v.x, sx = hh.x - v.x;
        float py = a.y + d.y, qy = a.y - d.y, ry = hh.y + v.y, sy = hh.y - v.y;

        f32x4 r0, r1;
        r0.x = (px + rx) * 0.5f;  r0.y = (qx + sx) * 0.5f;   // row 2h:   o00 o01
        r0.z = (py + ry) * 0.5f;  r0.w = (qy + sy) * 0.5f;
        r1.x = (qx - sx) * 0.5f;  r1.y = (px - rx) * 0.5f;   // row 2h+1: o10 o11
        r1.z = (qy - sy) * 0.5f;  r1.w = (py - ry) * 0.5f;

        int oo = (h << 6) + w2;
        ob[oo]      = r0;
        ob[oo + 32] = r1;
    }
}

extern "C" void kernel_launch(void* const* d_in, const int* in_sizes, int n_in,
                              void* d_out, int out_size, void* d_ws, size_t ws_size,
                              hipStream_t stream) {
    const float* x = (const float*)d_in[0];
    f32x4* out = (f32x4*)d_out;

    iwt_kernel<<<NBLOCK, NTHREAD, 0, stream>>>(x, out);
}

// Round 9
// 219.330 us; speedup vs baseline: 1.0582x; 1.0582x over previous
//
#include <hip/hip_runtime.h>

// IWT (inverse 2x2 Haar): x (32, 256, 64, 64) f32 -> out (32, 64, 128, 128) f32
// Input channel dim = 64 groups * 4 subbands {cA, cH, cV, cD}.
// out[2h  ][2w  ] = (a + h + v + d) * 0.5
// out[2h  ][2w+1] = (a + h - v - d) * 0.5
// out[2h+1][2w  ] = (a - h + v - d) * 0.5
// out[2h+1][2w+1] = (a - h - v + d) * 0.5
//
// v7 = v1 restored (the measured champion, 221.5 us harness dur).
// Session evidence (v1..v6): every structural lever was null or negative —
//   v2  float4 loads + stride-2 stores : 228.2
//   v3b persistent grid + NT stores    : 227.1
//   v4  2-tile ILP batching            : 228.6
//   v5  1024-thread blocks             : 223.5
//   v6  LDS-staged copy-shaped DRAM    : 232.1
// All six variants' dispatches land in a 72-84 us band with nothing
// saturated (HBM <= 31% demand, VALU ~5%, LDS 0, occupancy 15-63%) and
// duration ~= the harness's 512 MiB poison-fill time — the limiter is
// shared-BW contention with reset traffic in the timed window, not the
// kernel. Demand traffic is already minimal (268 MB, zero amplification;
// every vmem instruction fully dense). Keep the simplest, fastest form:
//   thread -> input float2 (w = 2*w2, 2*w2+1); 4x dwordx2 loads, each wave
//   load = 512B contiguous; 2x dwordx4 stores, each wave store = two dense
//   512B row segments. 20 VGPR, no LDS.

#define BB 32
#define CC 64
#define HH 64
#define WW 64

__global__ __launch_bounds__(256) void iwt_kernel(const float* __restrict__ x,
                                                  float* __restrict__ out) {
    int tid = blockIdx.x * blockDim.x + threadIdx.x;

    int w2 = tid & 31;           // which float2 within the input row (0..31)
    int h  = (tid >> 5) & 63;    // input row
    int bc = tid >> 11;          // 0 .. B*C-1 (2047)

    const float2* __restrict__ xv = (const float2*)x;
    // float idx for subband s: (4*bc + s)*4096 + h*64 + 2*w2
    // -> float2 idx: (4*bc + s)*2048 + h*32 + w2
    int base = (bc << 13) + (h << 5) + w2;
    float2 a  = xv[base];
    float2 hh = xv[base + 2048];
    float2 v  = xv[base + 4096];
    float2 d  = xv[base + 6144];

    // butterfly: p=a+d, q=a-d, r=h+v, s=h-v
    // o00=(p+r)/2, o01=(q+s)/2, o10=(q-s)/2, o11=(p-r)/2
    float px = a.x + d.x, qx = a.x - d.x, rx = hh.x + v.x, sx = hh.x - v.x;
    float py = a.y + d.y, qy = a.y - d.y, ry = hh.y + v.y, sy = hh.y - v.y;

    float4 r0, r1;
    r0.x = (px + rx) * 0.5f;   // o00 (w=2*w2)
    r0.y = (qx + sx) * 0.5f;   // o01
    r0.z = (py + ry) * 0.5f;   // o00 (w=2*w2+1)
    r0.w = (qy + sy) * 0.5f;   // o01
    r1.x = (qx - sx) * 0.5f;   // o10
    r1.y = (px - rx) * 0.5f;   // o11
    r1.z = (qy - sy) * 0.5f;   // o10
    r1.w = (py - ry) * 0.5f;   // o11

    float4* __restrict__ ov = (float4*)out;
    // out float4 idx for row y: (bc*128 + y)*32 + w2
    // row 2h:  bc*4096 + h*64 + w2 ; row 2h+1: +32
    int obase0 = (bc << 12) + (h << 6) + w2;
    ov[obase0]      = r0;
    ov[obase0 + 32] = r1;
}

extern "C" void kernel_launch(void* const* d_in, const int* in_sizes, int n_in,
                              void* d_out, int out_size, void* d_ws, size_t ws_size,
                              hipStream_t stream) {
    const float* x = (const float*)d_in[0];
    float* out = (float*)d_out;

    const int total_threads = BB * CC * HH * (WW / 2);  // 4,194,304
    const int block = 256;
    const int grid = total_threads / block;             // 16384

    iwt_kernel<<<grid, block, 0, stream>>>(x, out);
}